// Round 3
// baseline (21870.703 us; speedup 1.0000x reference)
//
#include <hip/hip_runtime.h>
#include <hip/hip_cooperative_groups.h>
#include <math.h>

namespace cg = cooperative_groups;

#define D 256
#define NH 4
#define HDIM 64
#define FFD 2048
#define NL 3
#define VOC 30000
#define BPTT 20
#define BATCH 64
#define NMAX (BPTT*BATCH)   /* 1280 */

struct Args {
  const float* image_feats; const int* target; const float* emb_table;
  const float* W_g2e; const float* b_g2e; const float* W_out; const float* b_out;
  const float* Wqkv; const float* bqkv; const float* Wo; const float* bo;
  const float* W1; const float* b1; const float* W2; const float* b2;
  const float* g1; const float* be1; const float* g2; const float* be2;
  float* out_probs; float* out_words; float* out_eos;
  float* embeds; float* xbuf; float* qkvb; float* obuf; float* pbuf; float* ffb; float* logits;
  int* maskb;
};

// ---------------- device helpers (shared by mega + fallback) ----------------

// GEMM tile: 8 tokens x 256 cols, 256 threads, acc[2][4]/thread. klen may span
// multiple 256-chunks. kbeg for split-K. Stores to C (guarded col<M).
__device__ __forceinline__ void gemm_tile(
    float* As, const float* __restrict__ A, int lda,
    const float* __restrict__ W, const float* __restrict__ bias,
    float* __restrict__ C, int M, int klen, int kbeg, int relu,
    int tok0, int colb, int tid)
{
  const int colg = tid & 63;
  const int tokg = tid >> 6;
  const int col  = colb + colg*4;
  int colL = col; if (colL > M-4) colL = M-4;

  float acc[2][4] = {{0.f,0.f,0.f,0.f},{0.f,0.f,0.f,0.f}};

  for (int k0 = 0; k0 < klen; k0 += 256) {
    __syncthreads();
#pragma unroll
    for (int j = 0; j < 8; ++j)
      As[j*256 + tid] = A[(long)(tok0 + j)*lda + kbeg + k0 + tid];
    __syncthreads();
    const float* Wp = W + (long)(kbeg + k0)*M + colL;
#pragma unroll 2
    for (int kk = 0; kk < 256; kk += 4) {
      float a0[4], a1[4], w[4][4];
      *(float4*)a0   = *(const float4*)&As[(tokg*2+0)*256 + kk];
      *(float4*)a1   = *(const float4*)&As[(tokg*2+1)*256 + kk];
      *(float4*)w[0] = *(const float4*)(Wp + (long)(kk+0)*M);
      *(float4*)w[1] = *(const float4*)(Wp + (long)(kk+1)*M);
      *(float4*)w[2] = *(const float4*)(Wp + (long)(kk+2)*M);
      *(float4*)w[3] = *(const float4*)(Wp + (long)(kk+3)*M);
#pragma unroll
      for (int c = 0; c < 4; ++c)
#pragma unroll
        for (int q = 0; q < 4; ++q) {
          acc[0][c] += a0[q] * w[q][c];
          acc[1][c] += a1[q] * w[q][c];
        }
    }
  }

  if (col < M) {
    float bv[4] = {0.f,0.f,0.f,0.f};
    if (bias) *(float4*)bv = *(const float4*)(bias + col);
#pragma unroll
    for (int j = 0; j < 2; ++j) {
      float v[4];
#pragma unroll
      for (int c = 0; c < 4; ++c) {
        v[c] = acc[j][c] + bv[c];
        if (relu) v[c] = fmaxf(v[c], 0.f);
      }
      *(float4*)(C + (long)(tok0 + tokg*2 + j)*M + col) = *(float4*)v;
    }
  }
}

// fused: out = LN(X + Aop@W + bias) for 8 tokens, M=K=256.
__device__ __forceinline__ void projln_tile(
    float* As, const float* __restrict__ Aop, const float* __restrict__ W,
    const float* __restrict__ X, const float* __restrict__ bias,
    const float* __restrict__ g, const float* __restrict__ be,
    float* __restrict__ out, int tok0, int tid)
{
  const int colg = tid & 63;
  const int tokg = tid >> 6;
  const int col  = colg*4;

  float acc[2][4] = {{0.f,0.f,0.f,0.f},{0.f,0.f,0.f,0.f}};

  __syncthreads();
#pragma unroll
  for (int j = 0; j < 8; ++j)
    As[j*256 + tid] = Aop[(long)(tok0 + j)*D + tid];
  __syncthreads();
  const float* Wp = W + col;
#pragma unroll 2
  for (int kk = 0; kk < 256; kk += 4) {
    float a0[4], a1[4], w[4][4];
    *(float4*)a0   = *(const float4*)&As[(tokg*2+0)*256 + kk];
    *(float4*)a1   = *(const float4*)&As[(tokg*2+1)*256 + kk];
    *(float4*)w[0] = *(const float4*)(Wp + (long)(kk+0)*D);
    *(float4*)w[1] = *(const float4*)(Wp + (long)(kk+1)*D);
    *(float4*)w[2] = *(const float4*)(Wp + (long)(kk+2)*D);
    *(float4*)w[3] = *(const float4*)(Wp + (long)(kk+3)*D);
#pragma unroll
    for (int c = 0; c < 4; ++c)
#pragma unroll
      for (int q = 0; q < 4; ++q) {
        acc[0][c] += a0[q] * w[q][c];
        acc[1][c] += a1[q] * w[q][c];
      }
  }

  float bv[4], gv[4], bev[4];
  *(float4*)bv  = *(const float4*)(bias + col);
  *(float4*)gv  = *(const float4*)(g + col);
  *(float4*)bev = *(const float4*)(be + col);

#pragma unroll
  for (int j = 0; j < 2; ++j) {
    const int tok = tok0 + tokg*2 + j;
    float v[4];
    float4 xv = *(const float4*)(X + (long)tok*D + col);
    v[0] = acc[j][0] + bv[0] + xv.x;
    v[1] = acc[j][1] + bv[1] + xv.y;
    v[2] = acc[j][2] + bv[2] + xv.z;
    v[3] = acc[j][3] + bv[3] + xv.w;
    float s = v[0]+v[1]+v[2]+v[3];
#pragma unroll
    for (int off = 1; off < 64; off <<= 1) s += __shfl_xor(s, off);
    float mu = s * (1.0f/D);
    float q0=v[0]-mu, q1=v[1]-mu, q2=v[2]-mu, q3=v[3]-mu;
    float q = q0*q0+q1*q1+q2*q2+q3*q3;
#pragma unroll
    for (int off = 1; off < 64; off <<= 1) q += __shfl_xor(q, off);
    float inv = 1.0f / sqrtf(q * (1.0f/D) + 1e-5f);
    float o[4];
    o[0] = q0*inv*gv[0] + bev[0];
    o[1] = q1*inv*gv[1] + bev[1];
    o[2] = q2*inv*gv[2] + bev[2];
    o[3] = q3*inv*gv[3] + bev[3];
    *(float4*)(out + (long)tok*D + col) = *(float4*)o;
  }
}

// residual + bias + sum of 4 partials -> LN, one token, 256 threads.
__device__ __forceinline__ void resln_token(
    const float* __restrict__ x, const float* __restrict__ parts, long pstride,
    const float* __restrict__ bias, const float* __restrict__ g,
    const float* __restrict__ be, float* __restrict__ out,
    int tok, int tid, float* red)
{
  float v = x[(long)tok*D + tid] + bias[tid];
#pragma unroll
  for (int p = 0; p < 4; ++p) v += parts[(long)p*pstride + (long)tok*D + tid];
  float s = v;
  for (int off = 32; off; off >>= 1) s += __shfl_down(s, off);
  if ((tid & 63) == 0) red[tid >> 6] = s;
  __syncthreads();
  float mu = (red[0]+red[1]+red[2]+red[3]) * (1.0f/D);
  __syncthreads();
  float dv = v - mu;
  float q = dv*dv;
  for (int off = 32; off; off >>= 1) q += __shfl_down(q, off);
  if ((tid & 63) == 0) red[tid >> 6] = q;
  __syncthreads();
  float var = (red[0]+red[1]+red[2]+red[3]) * (1.0f/D);
  out[(long)tok*D + tid] = dv * (1.0f/sqrtf(var + 1e-5f)) * g[tid] + be[tid];
  __syncthreads();
}

// attention for one (b,h), 256 threads. LDS layout inside sm (4352 floats):
// qs[0..1279], ks[1280..2639] (stride 68, conflict-free), vs[2640..3919], ps[3920..4339]
__device__ __forceinline__ void attn_unit(
    float* sm, const float* __restrict__ qkv, float* __restrict__ o,
    int S, int unit, int tid)
{
  float* qs = sm;
  float* ks = sm + 1280;
  float* vs = sm + 2640;
  float* ps = sm + 3920;
  const int b = unit & 63, h = unit >> 6;
  __syncthreads();
  for (int idx = tid; idx < S*HDIM; idx += 256) {
    int s = idx >> 6, dd = idx & 63;
    long base = (long)(s*BATCH + b)*(3*D) + h*HDIM + dd;
    qs[idx]        = qkv[base];
    ks[s*68 + dd]  = qkv[base + D];
    vs[idx]        = qkv[base + 2*D];
  }
  __syncthreads();
  for (int p = tid; p < S*S; p += 256) {
    int si = p / S, ti = p - si*S;
    float acc = 0.f;
#pragma unroll 8
    for (int k = 0; k < HDIM; ++k) acc += qs[si*HDIM + k] * ks[ti*68 + k];
    ps[si*(BPTT+1) + ti] = acc * 0.125f;
  }
  __syncthreads();
  if (tid < S) {
    float m = -1e30f;
    for (int t = 0; t < S; ++t) m = fmaxf(m, ps[tid*(BPTT+1)+t]);
    float sum = 0.f;
    for (int t = 0; t < S; ++t) { float e = expf(ps[tid*(BPTT+1)+t] - m); ps[tid*(BPTT+1)+t] = e; sum += e; }
    float inv = 1.0f / sum;
    for (int t = 0; t < S; ++t) ps[tid*(BPTT+1)+t] *= inv;
  }
  __syncthreads();
  for (int idx = tid; idx < S*HDIM; idx += 256) {
    int s = idx >> 6, dd = idx & 63;
    float acc = 0.f;
    for (int t = 0; t < S; ++t) acc += ps[s*(BPTT+1)+t] * vs[t*HDIM + dd];
    o[(long)(s*BATCH + b)*D + h*HDIM + dd] = acc;
  }
}

// vocab softmax/argmax/outputs/next-embed for one b, 256 threads.
__device__ __forceinline__ void vocab_unit(
    float* redf, int* redi,
    const float* __restrict__ logits, const int* __restrict__ mask,
    float* __restrict__ out_probs, float* __restrict__ out_words, float* __restrict__ out_eos,
    const float* __restrict__ emb, float* __restrict__ embeds, int step, int b, int tid)
{
  const float* lrow = logits + (long)b*VOC;
  __syncthreads();
  float m = -1e30f;
  for (int c = tid; c < VOC; c += 256) m = fmaxf(m, lrow[c]);
  for (int off = 32; off; off >>= 1) m = fmaxf(m, __shfl_down(m, off));
  if ((tid & 63) == 0) redf[tid >> 6] = m;
  __syncthreads();
  float gmax = fmaxf(fmaxf(redf[0],redf[1]), fmaxf(redf[2],redf[3]));
  __syncthreads();

  float s = 0.f, em = -1.0f;
  int ei = VOC;
  for (int c = tid; c < VOC; c += 256) {
    float e = expf(lrow[c] - gmax);
    s += e;
    if (e > em) { em = e; ei = c; }
  }
  for (int off = 32; off; off >>= 1) {
    float em2 = __shfl_down(em, off);
    int   ei2 = __shfl_down(ei, off);
    if (em2 > em || (em2 == em && ei2 < ei)) { em = em2; ei = ei2; }
    s += __shfl_down(s, off);
  }
  if ((tid & 63) == 0) { redf[4+(tid>>6)] = s; redf[8+(tid>>6)] = em; redi[tid>>6] = ei; }
  __syncthreads();
  float Ssum = redf[4]+redf[5]+redf[6]+redf[7];
  em = redf[8]; ei = redi[0];
  for (int w = 1; w < 4; ++w)
    if (redf[8+w] > em || (redf[8+w] == em && redi[w] < ei)) { em = redf[8+w]; ei = redi[w]; }

  int mk = mask[b*BPTT + step];
  for (int c = tid; c < VOC; c += 256) {
    float p = expf(lrow[c] - gmax) / Ssum;
    float* op = out_probs + (long)b*VOC + c;
    if (step == 0) *op = p;
    else if (mk)   *op = fmaxf(*op, p);
    if (c == 2) out_eos[b*BPTT + step] = p;
  }
  if (tid == 0) out_words[b*BPTT + step] = mk ? (float)ei : 0.0f;
  if (step + 1 < BPTT)
    embeds[(long)((step+1)*BATCH + b)*D + tid] = emb[(long)ei*D + tid];
  __syncthreads();
}

__device__ __forceinline__ void img_unit(
    float* xs, const float* __restrict__ feats, const float* __restrict__ Wg,
    const float* __restrict__ bg, float* __restrict__ embeds, int b, int tid)
{
  __syncthreads();
  for (int j = 0; j < 8; ++j) xs[tid + j*256] = feats[b*2048 + tid + j*256];
  __syncthreads();
  float acc = 0.f;
  for (int k = 0; k < 2048; k += 4) {
    float4 xv = *(const float4*)&xs[k];
    acc += xv.x * Wg[(k+0)*D + tid];
    acc += xv.y * Wg[(k+1)*D + tid];
    acc += xv.z * Wg[(k+2)*D + tid];
    acc += xv.w * Wg[(k+3)*D + tid];
  }
  embeds[b*D + tid] = acc + bg[tid];
}

// ---------------- the cooperative megakernel ----------------
__global__ __launch_bounds__(256, 2) void mega(Args a) {
  __shared__ float sm[4352];
  __shared__ float redf[16];
  __shared__ int   redi[4];
  cg::grid_group grid = cg::this_grid();
  const int tid = threadIdx.x;
  const int nb  = gridDim.x;

  // phase 0: mask (block 0) + img embed (64 tasks)
  if (blockIdx.x == 0 && tid < 64) {
    int b = tid, run = 1;
    for (int j = 0; j < BPTT; ++j) {
      if (j > 0 && a.target[b*BPTT + j] == 2) run = 0;
      a.maskb[b*BPTT + j] = run;
    }
  }
  for (int t = blockIdx.x; t < BATCH; t += nb)
    img_unit(sm, a.image_feats, a.W_g2e, a.b_g2e, a.embeds, t, tid);
  grid.sync();

  for (int i = 0; i < BPTT; ++i) {
    const int S = i + 1, N = S * BATCH, ntt = N / 8;
    for (int l = 0; l < NL; ++l) {
      const float* X = (l == 0) ? a.embeds : a.xbuf;
      // QKV: (ntt x 3) tiles
      for (int t = blockIdx.x; t < ntt*3; t += nb) {
        int tt = t % ntt, cb = t / ntt;
        gemm_tile(sm, X, D, a.Wqkv + (long)l*D*3*D, a.bqkv + (long)l*3*D,
                  a.qkvb, 3*D, 256, 0, 0, tt*8, cb*256, tid);
      }
      grid.sync();
      // attention: 256 units
      for (int t = blockIdx.x; t < BATCH*NH; t += nb)
        attn_unit(sm, a.qkvb, a.obuf, S, t, tid);
      grid.sync();
      // projLN: ntt tiles
      for (int t = blockIdx.x; t < ntt; t += nb)
        projln_tile(sm, a.obuf, a.Wo + (long)l*D*D, X, a.bo + (long)l*D,
                    a.g1 + (long)l*D, a.be1 + (long)l*D, a.xbuf, t*8, tid);
      grid.sync();
      // FF1: (ntt x 8) tiles
      for (int t = blockIdx.x; t < ntt*8; t += nb) {
        int tt = t % ntt, cb = t / ntt;
        gemm_tile(sm, a.xbuf, D, a.W1 + (long)l*D*FFD, a.b1 + (long)l*FFD,
                  a.ffb, FFD, 256, 0, 1, tt*8, cb*256, tid);
      }
      grid.sync();
      // FF2 split-K4: (ntt x 4) tiles
      for (int t = blockIdx.x; t < ntt*4; t += nb) {
        int tt = t % ntt, z = t / ntt;
        gemm_tile(sm, a.ffb, FFD, a.W2 + (long)l*FFD*D, nullptr,
                  a.pbuf + (long)z*NMAX*D, D, 512, z*512, 0, tt*8, 0, tid);
      }
      grid.sync();
      // resLN2: N tokens
      for (int t = blockIdx.x; t < N; t += nb)
        resln_token(a.xbuf, a.pbuf, (long)NMAX*D, a.b2 + (long)l*D,
                    a.g2 + (long)l*D, a.be2 + (long)l*D, a.xbuf, t, tid, redf);
      grid.sync();
    }
    // logits: 8 x 118 tiles over last-step token rows
    const float* Xl = a.xbuf + (long)i*BATCH*D;
    for (int t = blockIdx.x; t < 8*118; t += nb) {
      int tt = t % 8, cb = t / 8;
      gemm_tile(sm, Xl, D, a.W_out, a.b_out, a.logits, VOC, 256, 0, 0, tt*8, cb*256, tid);
    }
    grid.sync();
    // vocab: 64 units
    for (int t = blockIdx.x; t < BATCH; t += nb)
      vocab_unit(redf, redi, a.logits, a.maskb, a.out_probs, a.out_words, a.out_eos,
                 a.emb_table, a.embeds, i, t, tid);
    grid.sync();
  }
}

// ---------------- fallback multi-kernel path ----------------
__global__ void k_mask(const int* __restrict__ ids, int* __restrict__ mask) {
  int b = threadIdx.x, run = 1;
  for (int j = 0; j < BPTT; ++j) {
    if (j > 0 && ids[b*BPTT + j] == 2) run = 0;
    mask[b*BPTT + j] = run;
  }
}
__global__ __launch_bounds__(256) void k_img(const float* f, const float* Wg, const float* bg, float* e) {
  __shared__ float xs[2048];
  img_unit(xs, f, Wg, bg, e, blockIdx.x, threadIdx.x);
}
__global__ __launch_bounds__(256) void k_gemm(const float* A, int lda, const float* W, const float* bias,
                                              float* C, long pstride, int klen, int M, int relu) {
  __shared__ float As[2048];
  gemm_tile(As, A, lda, W, bias, C + (long)blockIdx.z*pstride, M, klen, blockIdx.z*klen, relu,
            blockIdx.x*8, blockIdx.y*256, threadIdx.x);
}
__global__ __launch_bounds__(256) void k_projln(const float* Aop, const float* W, const float* X,
                                                const float* bias, const float* g, const float* be, float* out) {
  __shared__ float As[2048];
  projln_tile(As, Aop, W, X, bias, g, be, out, blockIdx.x*8, threadIdx.x);
}
__global__ __launch_bounds__(256) void k_resln(const float* x, const float* parts, long pstride,
                                               const float* bias, const float* g, const float* be, float* out) {
  __shared__ float red[4];
  resln_token(x, parts, pstride, bias, g, be, out, blockIdx.x, threadIdx.x, red);
}
__global__ __launch_bounds__(256) void k_attn(const float* qkv, float* o, int S) {
  __shared__ float sm[4352];
  attn_unit(sm, qkv, o, S, blockIdx.x, threadIdx.x);
}
__global__ __launch_bounds__(256) void k_vocab(const float* logits, const int* mask,
    float* out_probs, float* out_words, float* out_eos,
    const float* emb, float* embeds, int step) {
  __shared__ float redf[16];
  __shared__ int   redi[4];
  vocab_unit(redf, redi, logits, mask, out_probs, out_words, out_eos, emb, embeds, step,
             blockIdx.x, threadIdx.x);
}

// ---------------- host ----------------
extern "C" void kernel_launch(void* const* d_in, const int* in_sizes, int n_in,
                              void* d_out, int out_size, void* d_ws, size_t ws_size,
                              hipStream_t stream) {
  Args a;
  a.image_feats = (const float*)d_in[0];
  a.target      = (const int*)  d_in[1];
  a.emb_table   = (const float*)d_in[2];
  a.W_g2e       = (const float*)d_in[3];
  a.b_g2e       = (const float*)d_in[4];
  a.W_out       = (const float*)d_in[5];
  a.b_out       = (const float*)d_in[6];
  a.Wqkv        = (const float*)d_in[7];
  a.bqkv        = (const float*)d_in[8];
  a.Wo          = (const float*)d_in[9];
  a.bo          = (const float*)d_in[10];
  a.W1          = (const float*)d_in[11];
  a.b1          = (const float*)d_in[12];
  a.W2          = (const float*)d_in[13];
  a.b2          = (const float*)d_in[14];
  a.g1          = (const float*)d_in[15];
  a.be1         = (const float*)d_in[16];
  a.g2          = (const float*)d_in[17];
  a.be2         = (const float*)d_in[18];

  a.out_probs = (float*)d_out;
  a.out_words = a.out_probs + (long)BATCH*VOC;
  a.out_eos   = a.out_words + BATCH*BPTT;

  char* ws = (char*)d_ws;
  a.embeds = (float*)ws;  ws += sizeof(float)*(long)NMAX*D;
  a.xbuf   = (float*)ws;  ws += sizeof(float)*(long)NMAX*D;
  a.qkvb   = (float*)ws;  ws += sizeof(float)*(long)NMAX*3*D;
  a.obuf   = (float*)ws;  ws += sizeof(float)*(long)NMAX*D;
  a.pbuf   = (float*)ws;  ws += sizeof(float)*(long)4*NMAX*D;
  a.ffb    = (float*)ws;  ws += sizeof(float)*(long)NMAX*FFD;
  a.logits = (float*)ws;  ws += sizeof(float)*(long)BATCH*VOC;
  a.maskb  = (int*)ws;    ws += sizeof(int)*BATCH*BPTT;

  int occ = 0;
  hipError_t oe = hipOccupancyMaxActiveBlocksPerMultiprocessor(&occ, (const void*)mega, 256, 0);
  if (oe != hipSuccess || occ < 1) occ = 1;
  int grid = occ * 256;
  if (grid > 512) grid = 512;

  void* params[1] = { (void*)&a };
  hipError_t e = hipLaunchCooperativeKernel((const void*)mega, dim3(grid), dim3(256), params, 0, stream);

  if (e != hipSuccess) {
    // fallback: equivalent multi-kernel sequence
    k_mask<<<1, 64, 0, stream>>>(a.target, a.maskb);
    k_img<<<BATCH, 256, 0, stream>>>(a.image_feats, a.W_g2e, a.b_g2e, a.embeds);
    for (int i = 0; i < BPTT; ++i) {
      int S = i+1, N = S*BATCH, ntt = N/8;
      for (int l = 0; l < NL; ++l) {
        const float* X = (l == 0) ? a.embeds : a.xbuf;
        k_gemm<<<dim3(ntt,3,1), 256, 0, stream>>>(X, D, a.Wqkv + (long)l*D*3*D, a.bqkv + (long)l*3*D,
                                                  a.qkvb, 0, 256, 3*D, 0);
        k_attn<<<dim3(BATCH*NH), 256, 0, stream>>>(a.qkvb, a.obuf, S);
        k_projln<<<dim3(ntt), 256, 0, stream>>>(a.obuf, a.Wo + (long)l*D*D, X, a.bo + (long)l*D,
                                                a.g1 + (long)l*D, a.be1 + (long)l*D, a.xbuf);
        k_gemm<<<dim3(ntt,8,1), 256, 0, stream>>>(a.xbuf, D, a.W1 + (long)l*D*FFD, a.b1 + (long)l*FFD,
                                                  a.ffb, 0, 256, FFD, 1);
        k_gemm<<<dim3(ntt,1,4), 256, 0, stream>>>(a.ffb, FFD, a.W2 + (long)l*FFD*D, nullptr,
                                                  a.pbuf, (long)NMAX*D, 512, D, 0);
        k_resln<<<dim3(N), 256, 0, stream>>>(a.xbuf, a.pbuf, (long)NMAX*D, a.b2 + (long)l*D,
                                             a.g2 + (long)l*D, a.be2 + (long)l*D, a.xbuf);
      }
      k_gemm<<<dim3(8,118,1), 256, 0, stream>>>(a.xbuf + (long)i*BATCH*D, D, a.W_out, a.b_out,
                                                a.logits, 0, 256, VOC, 0);
      k_vocab<<<dim3(BATCH), 256, 0, stream>>>(a.logits, a.maskb, a.out_probs, a.out_words, a.out_eos,
                                               a.emb_table, a.embeds, i);
    }
  }
}

// Round 4
// 17236.746 us; speedup vs baseline: 1.2688x; 1.2688x over previous
//
#include <hip/hip_runtime.h>
#include <math.h>

#define D 256
#define NH 4
#define HDIM 64
#define FFD 2048
#define NL 3
#define VOC 30000
#define BPTT 20
#define BATCH 64
#define NMAX (BPTT*BATCH)   /* 1280 */

// ---------------- img embed (+ mask in block 0) ----------------
__global__ __launch_bounds__(256) void k_img(const float* __restrict__ feats,
                                             const float* __restrict__ Wg,
                                             const float* __restrict__ bg,
                                             float* __restrict__ embeds,
                                             const int* __restrict__ ids,
                                             int* __restrict__ mask) {
  __shared__ float xs[2048];
  int b = blockIdx.x, tid = threadIdx.x;
  if (b == 0 && tid < 64) {
    int run = 1;
    for (int j = 0; j < BPTT; ++j) {
      if (j > 0 && ids[tid*BPTT + j] == 2) run = 0;
      mask[tid*BPTT + j] = run;
    }
  }
  for (int j = 0; j < 8; ++j) xs[tid + j*256] = feats[b*2048 + tid + j*256];
  __syncthreads();
  float acc = 0.f;
  for (int k = 0; k < 2048; k += 4) {
    float4 xv = *(const float4*)&xs[k];
    acc += xv.x * Wg[(k+0)*D + tid];
    acc += xv.y * Wg[(k+1)*D + tid];
    acc += xv.z * Wg[(k+2)*D + tid];
    acc += xv.w * Wg[(k+3)*D + tid];
  }
  embeds[b*D + tid] = acc + bg[tid];
}

// ---------------- generic GEMM tile: 8 tok x 256 cols (FF1 / logits) ----------------
__global__ __launch_bounds__(256) void k_gemm(
    const float* __restrict__ A, int lda,
    const float* __restrict__ W,
    const float* __restrict__ bias,
    float* __restrict__ C, int M, int relu)
{
  __shared__ float As[2048];
  const int tid  = threadIdx.x;
  const int tok0 = blockIdx.x * 8;
  const int colb = blockIdx.y * 256;
  const int colg = tid & 63;
  const int tokg = tid >> 6;
  const int col  = colb + colg*4;
  int colL = col; if (colL > M-4) colL = M-4;

  float acc[2][4] = {{0.f,0.f,0.f,0.f},{0.f,0.f,0.f,0.f}};

  __syncthreads();
#pragma unroll
  for (int j = 0; j < 8; ++j)
    As[j*256 + tid] = A[(long)(tok0 + j)*lda + tid];
  __syncthreads();
  const float* Wp = W + colL;
#pragma unroll 2
  for (int kk = 0; kk < 256; kk += 4) {
    float a0[4], a1[4], w[4][4];
    *(float4*)a0   = *(const float4*)&As[(tokg*2+0)*256 + kk];
    *(float4*)a1   = *(const float4*)&As[(tokg*2+1)*256 + kk];
    *(float4*)w[0] = *(const float4*)(Wp + (long)(kk+0)*M);
    *(float4*)w[1] = *(const float4*)(Wp + (long)(kk+1)*M);
    *(float4*)w[2] = *(const float4*)(Wp + (long)(kk+2)*M);
    *(float4*)w[3] = *(const float4*)(Wp + (long)(kk+3)*M);
#pragma unroll
    for (int c = 0; c < 4; ++c)
#pragma unroll
      for (int q = 0; q < 4; ++q) {
        acc[0][c] += a0[q] * w[q][c];
        acc[1][c] += a1[q] * w[q][c];
      }
  }

  if (col < M) {
    float bv[4] = {0.f,0.f,0.f,0.f};
    if (bias) *(float4*)bv = *(const float4*)(bias + col);
#pragma unroll
    for (int j = 0; j < 2; ++j) {
      float v[4];
#pragma unroll
      for (int c = 0; c < 4; ++c) {
        v[c] = acc[j][c] + bv[c];
        if (relu) v[c] = fmaxf(v[c], 0.f);
      }
      *(float4*)(C + (long)(tok0 + tokg*2 + j)*M + col) = *(float4*)v;
    }
  }
}

// ---------------- fused attention: qkv-gen + scores + softmax + PV, one (b,h) ----------------
__global__ __launch_bounds__(256) void k_attn2(const float* __restrict__ X,
                                               const float* __restrict__ Wqkv_l,
                                               const float* __restrict__ bqkv_l,
                                               float* __restrict__ o, int S)
{
  __shared__ float xs[BPTT*256];     // 20 KB
  __shared__ float qs[BPTT*68], ks[BPTT*68], vs[BPTT*68];
  __shared__ float ps[BPTT*21];
  const int unit = blockIdx.x, b = unit & 63, h = unit >> 6, tid = threadIdx.x;

  for (int idx = tid; idx < S*256; idx += 256) {
    int s = idx >> 8, k = idx & 255;
    xs[idx] = X[(long)(s*BATCH + b)*D + k];
  }
  __syncthreads();

  if (tid < 192) {
    const int j = tid >> 6, dd = tid & 63;
    const int colW = j*D + h*HDIM + dd;
    float acc[BPTT];
#pragma unroll
    for (int s = 0; s < BPTT; ++s) acc[s] = 0.f;
    for (int k = 0; k < 256; ++k) {
      float w = Wqkv_l[(long)k*(3*D) + colW];
#pragma unroll
      for (int s = 0; s < BPTT; ++s) acc[s] += xs[s*256 + k] * w;
    }
    float bqv = bqkv_l[colW];
    float* dst = (j == 0) ? qs : (j == 1) ? ks : vs;
#pragma unroll
    for (int s = 0; s < BPTT; ++s) dst[s*68 + dd] = acc[s] + bqv;
  }
  __syncthreads();

  for (int p = tid; p < S*S; p += 256) {
    int si = p / S, ti = p - si*S;
    float a = 0.f;
#pragma unroll 8
    for (int k = 0; k < HDIM; ++k) a += qs[si*68 + k] * ks[ti*68 + k];
    ps[si*21 + ti] = a * 0.125f;
  }
  __syncthreads();
  if (tid < S) {
    float m = -1e30f;
    for (int t = 0; t < S; ++t) m = fmaxf(m, ps[tid*21 + t]);
    float sum = 0.f;
    for (int t = 0; t < S; ++t) { float e = expf(ps[tid*21 + t] - m); ps[tid*21 + t] = e; sum += e; }
    float inv = 1.0f / sum;
    for (int t = 0; t < S; ++t) ps[tid*21 + t] *= inv;
  }
  __syncthreads();
  for (int idx = tid; idx < S*HDIM; idx += 256) {
    int s = idx >> 6, dd = idx & 63;
    float a = 0.f;
    for (int t = 0; t < S; ++t) a += ps[s*21 + t] * vs[t*68 + dd];
    o[(long)(s*BATCH + b)*D + h*HDIM + dd] = a;
  }
}

// ---------------- fused: out = LN(X + o@Wo + bo), 8 tok x 256 cols ----------------
__global__ __launch_bounds__(256) void k_projln(
    const float* __restrict__ Aop, const float* __restrict__ W,
    const float* __restrict__ X, const float* __restrict__ bias,
    const float* __restrict__ g, const float* __restrict__ be,
    float* __restrict__ out)
{
  __shared__ float As[2048];
  const int tid  = threadIdx.x;
  const int tok0 = blockIdx.x * 8;
  const int colg = tid & 63;
  const int tokg = tid >> 6;
  const int col  = colg*4;

  float acc[2][4] = {{0.f,0.f,0.f,0.f},{0.f,0.f,0.f,0.f}};

  __syncthreads();
#pragma unroll
  for (int j = 0; j < 8; ++j)
    As[j*256 + tid] = Aop[(long)(tok0 + j)*D + tid];
  __syncthreads();
  const float* Wp = W + col;
#pragma unroll 2
  for (int kk = 0; kk < 256; kk += 4) {
    float a0[4], a1[4], w[4][4];
    *(float4*)a0   = *(const float4*)&As[(tokg*2+0)*256 + kk];
    *(float4*)a1   = *(const float4*)&As[(tokg*2+1)*256 + kk];
    *(float4*)w[0] = *(const float4*)(Wp + (long)(kk+0)*D);
    *(float4*)w[1] = *(const float4*)(Wp + (long)(kk+1)*D);
    *(float4*)w[2] = *(const float4*)(Wp + (long)(kk+2)*D);
    *(float4*)w[3] = *(const float4*)(Wp + (long)(kk+3)*D);
#pragma unroll
    for (int c = 0; c < 4; ++c)
#pragma unroll
      for (int q = 0; q < 4; ++q) {
        acc[0][c] += a0[q] * w[q][c];
        acc[1][c] += a1[q] * w[q][c];
      }
  }

  float bv[4], gv[4], bev[4];
  *(float4*)bv  = *(const float4*)(bias + col);
  *(float4*)gv  = *(const float4*)(g + col);
  *(float4*)bev = *(const float4*)(be + col);

#pragma unroll
  for (int j = 0; j < 2; ++j) {
    const int tok = tok0 + tokg*2 + j;
    float v[4];
    float4 xv = *(const float4*)(X + (long)tok*D + col);
    v[0] = acc[j][0] + bv[0] + xv.x;
    v[1] = acc[j][1] + bv[1] + xv.y;
    v[2] = acc[j][2] + bv[2] + xv.z;
    v[3] = acc[j][3] + bv[3] + xv.w;
    float s = v[0]+v[1]+v[2]+v[3];
#pragma unroll
    for (int off = 1; off < 64; off <<= 1) s += __shfl_xor(s, off);
    float mu = s * (1.0f/D);
    float q0=v[0]-mu, q1=v[1]-mu, q2=v[2]-mu, q3=v[3]-mu;
    float q = q0*q0+q1*q1+q2*q2+q3*q3;
#pragma unroll
    for (int off = 1; off < 64; off <<= 1) q += __shfl_xor(q, off);
    float inv = 1.0f / sqrtf(q * (1.0f/D) + 1e-5f);
    float ov[4];
    ov[0] = q0*inv*gv[0] + bev[0];
    ov[1] = q1*inv*gv[1] + bev[1];
    ov[2] = q2*inv*gv[2] + bev[2];
    ov[3] = q3*inv*gv[3] + bev[3];
    *(float4*)(out + (long)tok*D + col) = *(float4*)ov;
  }
}

// ---------------- fused: x = LN(x1 + ff@W2 + b2), 4 tok/block, full K=2048 ----------------
__global__ __launch_bounds__(256) void k_ff2ln(
    const float* __restrict__ ff, const float* __restrict__ W2,
    const float* __restrict__ x1, const float* __restrict__ b2,
    const float* __restrict__ g, const float* __restrict__ be,
    float* __restrict__ out)
{
  __shared__ float As[4*260];
  const int tid  = threadIdx.x;
  const int tok0 = blockIdx.x * 4;
  const int wave = tid >> 6;     // 4 waves <-> 4 tokens
  const int lane = tid & 63;
  const int col  = lane * 4;

  float acc[4] = {0.f,0.f,0.f,0.f};

  for (int k0 = 0; k0 < FFD; k0 += 256) {
    __syncthreads();
    {
      int r = tid >> 6, c = (tid & 63) * 4;   // 4 rows x 64 float4
      *(float4*)&As[r*260 + c] = *(const float4*)&ff[(long)(tok0 + r)*FFD + k0 + c];
    }
    __syncthreads();
    const float* Wp = W2 + (long)k0*D + col;
#pragma unroll 4
    for (int kk = 0; kk < 256; ++kk) {
      float a = As[wave*260 + kk];
      float4 w = *(const float4*)(Wp + (long)kk*D);
      acc[0] += a*w.x; acc[1] += a*w.y; acc[2] += a*w.z; acc[3] += a*w.w;
    }
  }

  const int tok = tok0 + wave;
  float bv[4], gv[4], bev[4], xv[4];
  *(float4*)bv  = *(const float4*)(b2 + col);
  *(float4*)gv  = *(const float4*)(g + col);
  *(float4*)bev = *(const float4*)(be + col);
  *(float4*)xv  = *(const float4*)(x1 + (long)tok*D + col);
  float v[4];
#pragma unroll
  for (int c = 0; c < 4; ++c) v[c] = acc[c] + bv[c] + xv[c];
  float s = v[0]+v[1]+v[2]+v[3];
#pragma unroll
  for (int off = 1; off < 64; off <<= 1) s += __shfl_xor(s, off);
  float mu = s * (1.0f/D);
  float q0=v[0]-mu, q1=v[1]-mu, q2=v[2]-mu, q3=v[3]-mu;
  float q = q0*q0+q1*q1+q2*q2+q3*q3;
#pragma unroll
  for (int off = 1; off < 64; off <<= 1) q += __shfl_xor(q, off);
  float inv = 1.0f / sqrtf(q * (1.0f/D) + 1e-5f);
  float ov[4];
  ov[0] = q0*inv*gv[0] + bev[0];
  ov[1] = q1*inv*gv[1] + bev[1];
  ov[2] = q2*inv*gv[2] + bev[2];
  ov[3] = q3*inv*gv[3] + bev[3];
  *(float4*)(out + (long)tok*D + col) = *(float4*)ov;
}

// ---------------- vocab softmax + argmax + outputs + next-embed ----------------
__global__ __launch_bounds__(256) void k_vocab(
    const float* __restrict__ logits, const int* __restrict__ mask,
    float* __restrict__ out_probs, float* __restrict__ out_words, float* __restrict__ out_eos,
    const float* __restrict__ emb, float* __restrict__ embeds, int step)
{
  __shared__ float redf[12];
  __shared__ int   redi[4];
  int b = blockIdx.x, tid = threadIdx.x;
  const float* lrow = logits + (long)b*VOC;

  float m = -1e30f;
  for (int c = tid; c < VOC; c += 256) m = fmaxf(m, lrow[c]);
  for (int off = 32; off; off >>= 1) m = fmaxf(m, __shfl_down(m, off));
  if ((tid & 63) == 0) redf[tid >> 6] = m;
  __syncthreads();
  float gmax = fmaxf(fmaxf(redf[0],redf[1]), fmaxf(redf[2],redf[3]));
  __syncthreads();

  float s = 0.f, em = -1.0f;
  int ei = VOC;
  for (int c = tid; c < VOC; c += 256) {
    float e = expf(lrow[c] - gmax);
    s += e;
    if (e > em) { em = e; ei = c; }
  }
  for (int off = 32; off; off >>= 1) {
    float em2 = __shfl_down(em, off);
    int   ei2 = __shfl_down(ei, off);
    if (em2 > em || (em2 == em && ei2 < ei)) { em = em2; ei = ei2; }
    s += __shfl_down(s, off);
  }
  if ((tid & 63) == 0) { redf[4+(tid>>6)] = s; redf[8+(tid>>6)] = em; redi[tid>>6] = ei; }
  __syncthreads();
  float Ssum = redf[4]+redf[5]+redf[6]+redf[7];
  em = redf[8]; ei = redi[0];
  for (int w = 1; w < 4; ++w)
    if (redf[8+w] > em || (redf[8+w] == em && redi[w] < ei)) { em = redf[8+w]; ei = redi[w]; }

  int mk = mask[b*BPTT + step];
  for (int c = tid; c < VOC; c += 256) {
    float p = expf(lrow[c] - gmax) / Ssum;
    float* op = out_probs + (long)b*VOC + c;
    if (step == 0) *op = p;
    else if (mk)   *op = fmaxf(*op, p);
    if (c == 2) out_eos[b*BPTT + step] = p;
  }
  if (tid == 0) out_words[b*BPTT + step] = mk ? (float)ei : 0.0f;
  if (step + 1 < BPTT)
    embeds[(long)((step+1)*BATCH + b)*D + tid] = emb[(long)ei*D + tid];
}

// ---------------- host ----------------
extern "C" void kernel_launch(void* const* d_in, const int* in_sizes, int n_in,
                              void* d_out, int out_size, void* d_ws, size_t ws_size,
                              hipStream_t stream) {
  const float* image_feats = (const float*)d_in[0];
  const int*   target      = (const int*)  d_in[1];
  const float* emb_table   = (const float*)d_in[2];
  const float* W_g2e       = (const float*)d_in[3];
  const float* b_g2e       = (const float*)d_in[4];
  const float* W_out       = (const float*)d_in[5];
  const float* b_out       = (const float*)d_in[6];
  const float* Wqkv        = (const float*)d_in[7];
  const float* bqkv        = (const float*)d_in[8];
  const float* Wo          = (const float*)d_in[9];
  const float* bo          = (const float*)d_in[10];
  const float* W1          = (const float*)d_in[11];
  const float* b1          = (const float*)d_in[12];
  const float* W2          = (const float*)d_in[13];
  const float* b2          = (const float*)d_in[14];
  const float* g1          = (const float*)d_in[15];
  const float* be1         = (const float*)d_in[16];
  const float* g2          = (const float*)d_in[17];
  const float* be2         = (const float*)d_in[18];

  float* out_probs = (float*)d_out;
  float* out_words = out_probs + (long)BATCH*VOC;
  float* out_eos   = out_words + BATCH*BPTT;

  char* ws = (char*)d_ws;
  float* embeds = (float*)ws;  ws += sizeof(float)*(long)NMAX*D;
  float* xbuf   = (float*)ws;  ws += sizeof(float)*(long)NMAX*D;
  float* obuf   = (float*)ws;  ws += sizeof(float)*(long)NMAX*D;
  float* ffb    = (float*)ws;  ws += sizeof(float)*(long)NMAX*FFD;
  float* logits = (float*)ws;  ws += sizeof(float)*(long)BATCH*VOC;
  int*   maskb  = (int*)ws;    ws += sizeof(int)*BATCH*BPTT;

  k_img<<<BATCH, 256, 0, stream>>>(image_feats, W_g2e, b_g2e, embeds, target, maskb);

  for (int i = 0; i < BPTT; ++i) {
    const int S = i + 1, N = S * BATCH, ntt = N / 8;
    for (int l = 0; l < NL; ++l) {
      const float* X = (l == 0) ? embeds : xbuf;
      // fused qkv-gen + attention
      k_attn2<<<dim3(BATCH*NH), 256, 0, stream>>>(X, Wqkv + (long)l*D*3*D, bqkv + (long)l*3*D,
                                                  obuf, S);
      // x1 = LN(X + o@Wo + bo)
      k_projln<<<dim3(ntt), 256, 0, stream>>>(obuf, Wo + (long)l*D*D, X, bo + (long)l*D,
                                              g1 + (long)l*D, be1 + (long)l*D, xbuf);
      // ff = relu(x1 @ W1 + b1)
      k_gemm<<<dim3(ntt, FFD/256), 256, 0, stream>>>(xbuf, D, W1 + (long)l*D*FFD, b1 + (long)l*FFD,
                                                     ffb, FFD, 1);
      // x2 = LN(x1 + ff@W2 + b2)   (in-place on xbuf)
      k_ff2ln<<<dim3(N/4), 256, 0, stream>>>(ffb, W2 + (long)l*FFD*D, xbuf, b2 + (long)l*D,
                                             g2 + (long)l*D, be2 + (long)l*D, xbuf);
    }
    // logits for last-step token rows
    k_gemm<<<dim3(8, (VOC+255)/256), 256, 0, stream>>>(xbuf + (long)i*BATCH*D, D, W_out, b_out,
                                                       logits, VOC, 0);
    // vocab softmax/argmax/outputs/next-embed
    k_vocab<<<dim3(BATCH), 256, 0, stream>>>(logits, maskb, out_probs, out_words, out_eos,
                                             emb_table, embeds, i);
  }
}